// Round 5
// baseline (54.485 us; speedup 1.0000x reference)
//
#include <hip/hip_runtime.h>

#define NPART 4096
#define E_TOT 262144
#define HID   128
#define FDOF  6
#define BM    64                 // edges per block-iteration
#define NIT   (E_TOT / BM)       // 4096
#define GRID  768                // 3 blocks/CU (LDS-capped) x 256 CU
#define XPAD  48                 // bf16 per X row: 96 B = 6x16 -> aligned b128 reads
#define HPAD  136                // bf16 per H row: 272 B = 17x16 -> aligned

typedef __bf16 bf16x8 __attribute__((ext_vector_type(8)));
typedef float  f32x4  __attribute__((ext_vector_type(4)));

__global__ void pairvel_zero_kernel(float* __restrict__ out, int n) {
    const int i = blockIdx.x * blockDim.x + threadIdx.x;
    if (i < n) out[i] = 0.0f;
}

// 4-wave block; wave w owns hidden cols [32w,32w+32) for L1/L2, edge rows
// [16w,16w+16) for L3. Weights = per-wave MFMA B-fragments (56 VGPRs).
// Round 5: double-buffered Xs + register prefetch (T14) — next iter's
// gather issues before barrier (2) and its latency hides under the L2
// MFMA phase; barriers 4 -> 3 per iter.
__global__ __launch_bounds__(256) void pairvel_mfma_kernel(
    const float* __restrict__ rel,       // [N,N,3]
    const int*   __restrict__ tgt,       // [E]
    const int*   __restrict__ src,       // [E]
    const float* __restrict__ force,     // [N,6]
    const float* __restrict__ visc,
    const float* __restrict__ medianp,
    const float* __restrict__ contactp,
    const float* __restrict__ W1,        // [19,128]
    const float* __restrict__ b1,        // [128]
    const float* __restrict__ W2,        // [128,128]
    const float* __restrict__ b2,        // [128]
    const float* __restrict__ W3,        // [128,6]
    const float* __restrict__ b3,        // [6]
    float* __restrict__ out)             // [N,6]
{
    const int tid = threadIdx.x;
    const int w   = tid >> 6;     // wave 0..3
    const int l   = tid & 63;     // lane
    const int l15 = l & 15;
    const int lhi = l >> 4;       // 0..3

    // ---- weight fragments (B operand: lane l holds W[kt*32+lhi*8+r][n16+l15])
    bf16x8 w1f[2], w2f[4][2], w3f[4];
    #pragma unroll
    for (int nb = 0; nb < 2; ++nb) {
        const int n = (2 * w + nb) * 16 + l15;
        #pragma unroll
        for (int r = 0; r < 8; ++r) {
            const int k = lhi * 8 + r;
            w1f[nb][r] = (k < 19) ? (__bf16)W1[k * HID + n] : (__bf16)0.0f;
        }
    }
    #pragma unroll
    for (int kt = 0; kt < 4; ++kt)
        #pragma unroll
        for (int nb = 0; nb < 2; ++nb) {
            const int n = (2 * w + nb) * 16 + l15;
            #pragma unroll
            for (int r = 0; r < 8; ++r)
                w2f[kt][nb][r] = (__bf16)W2[(kt * 32 + lhi * 8 + r) * HID + n];
        }
    #pragma unroll
    for (int kt = 0; kt < 4; ++kt)
        #pragma unroll
        for (int r = 0; r < 8; ++r) {
            const int k = kt * 32 + lhi * 8 + r;
            w3f[kt][r] = (l15 < FDOF) ? (__bf16)W3[k * FDOF + l15] : (__bf16)0.0f;
        }

    const float b1v0 = b1[(2 * w) * 16 + l15];
    const float b1v1 = b1[(2 * w + 1) * 16 + l15];
    const float b2v0 = b2[(2 * w) * 16 + l15];
    const float b2v1 = b2[(2 * w + 1) * 16 + l15];
    const float b3v  = (l15 < FDOF) ? b3[l15] : 0.0f;
    const float inv_mu  = 1.0f / visc[0];
    const float median  = medianp[0];
    const float contact = contactp[0];

    __shared__ __align__(16) __bf16 Xs[2][BM][XPAD];
    __shared__ __align__(16) __bf16 H1s[BM][HPAD];
    __shared__ __align__(16) __bf16 H2s[BM][HPAD];
    __shared__ int tgts[2][BM];

    // zero X pad cols 19..31 in both buffers once (cols 32..47 never read)
    for (int t = tid; t < 2 * BM * 13; t += 256) {
        const int b = t / (BM * 13), rem = t % (BM * 13);
        Xs[b][rem / 13][19 + rem % 13] = (__bf16)0.0f;
    }

    // ---- per-thread prefetch state (8 scalars; no arrays -> no scratch) ----
    int   p_i0 = 0;
    float p_v0 = 0.f, p_v1 = 0.f, p_v2 = 0.f;
    float p_f3 = 0.f, p_f4 = 0.f, p_f5 = 0.f;

    auto gather_load = [&](int e0n) {
        if (tid < BM) {
            const int eg = e0n + tid;
            p_i0 = tgt[eg];
            const int sg = src[eg];
            const float* rp = rel + ((size_t)p_i0 * NPART + sg) * 3;
            p_v0 = rp[0]; p_v1 = rp[1]; p_v2 = rp[2];
        } else if (tid < 2 * BM) {
            const int eg = e0n + (tid - BM);
            const float2* f2 =
                reinterpret_cast<const float2*>(force + (size_t)tgt[eg] * FDOF);
            const float2 u0 = f2[0], u1 = f2[1], u2 = f2[2];
            p_v0 = u0.x; p_v1 = u0.y; p_v2 = u1.x;
            p_f3 = u1.y; p_f4 = u2.x; p_f5 = u2.y;
        } else if (tid < 3 * BM) {
            const int eg = e0n + (tid - 2 * BM);
            const float2* f2 =
                reinterpret_cast<const float2*>(force + (size_t)src[eg] * FDOF);
            const float2 u0 = f2[0], u1 = f2[1], u2 = f2[2];
            p_v0 = u0.x; p_v1 = u0.y; p_v2 = u1.x;
            p_f3 = u1.y; p_f4 = u2.x; p_f5 = u2.y;
        }
    };

    auto write_x = [&](int b) {
        if (tid < BM) {
            const int e = tid;
            tgts[b][e] = p_i0;
            const float dist = fmaxf(
                sqrtf(p_v0 * p_v0 + p_v1 * p_v1 + p_v2 * p_v2), 1e-8f);
            const float rs = (dist - median) * (dist - median);
            Xs[b][e][0] = (__bf16)p_v0;
            Xs[b][e][1] = (__bf16)p_v1;
            Xs[b][e][2] = (__bf16)p_v2;
            Xs[b][e][3] = (__bf16)dist;
            Xs[b][e][4] = (__bf16)rs;
            Xs[b][e][5] = (__bf16)(rs * rs);
            Xs[b][e][6] = (__bf16)(dist - contact);
        } else if (tid < 2 * BM) {
            const int e = tid - BM;
            Xs[b][e][7]  = (__bf16)p_v0;
            Xs[b][e][8]  = (__bf16)p_v1;
            Xs[b][e][9]  = (__bf16)p_v2;
            Xs[b][e][10] = (__bf16)p_f3;
            Xs[b][e][11] = (__bf16)p_f4;
            Xs[b][e][12] = (__bf16)p_f5;
        } else if (tid < 3 * BM) {
            const int e = tid - 2 * BM;
            Xs[b][e][13] = (__bf16)p_v0;
            Xs[b][e][14] = (__bf16)p_v1;
            Xs[b][e][15] = (__bf16)p_v2;
            Xs[b][e][16] = (__bf16)p_f3;
            Xs[b][e][17] = (__bf16)p_f4;
            Xs[b][e][18] = (__bf16)p_f5;
        }
    };

    // ---- prologue: stage iter-0 tile ---------------------------------------
    gather_load(blockIdx.x * BM);
    write_x(0);
    int buf = 0;

    for (int it = blockIdx.x; it < NIT; it += GRID) {
        __syncthreads();   // (1) Xs[buf]/tgts[buf] visible; H2s consumed

        // ---- layer 1: H1 = relu(X @ W1 + b1), wave w -> cols 32w..32w+31 ---
        #pragma unroll
        for (int m = 0; m < 4; ++m) {
            const bf16x8 a = *reinterpret_cast<const bf16x8*>(
                &Xs[buf][m * 16 + l15][lhi * 8]);
            #pragma unroll
            for (int nb = 0; nb < 2; ++nb) {
                const float bv = nb ? b1v1 : b1v0;
                f32x4 acc = { bv, bv, bv, bv };
                acc = __builtin_amdgcn_mfma_f32_16x16x32_bf16(
                          a, w1f[nb], acc, 0, 0, 0);
                #pragma unroll
                for (int r = 0; r < 4; ++r)
                    H1s[m * 16 + lhi * 4 + r][(2 * w + nb) * 16 + l15] =
                        (__bf16)fmaxf(acc[r], 0.0f);
            }
        }

        // ---- prefetch next tile into regs (latency hides under L2 phase) ---
        const bool havenext = (it + GRID) < NIT;
        if (havenext) gather_load((it + GRID) * BM);

        __syncthreads();   // (2) H1s ready; Xs[buf] fully read

        // ---- layer 2: H2 = relu(H1 @ W2 + b2) ------------------------------
        #pragma unroll
        for (int m = 0; m < 4; ++m) {
            f32x4 acc0 = { b2v0, b2v0, b2v0, b2v0 };
            f32x4 acc1 = { b2v1, b2v1, b2v1, b2v1 };
            #pragma unroll
            for (int kt = 0; kt < 4; ++kt) {
                const bf16x8 a = *reinterpret_cast<const bf16x8*>(
                    &H1s[m * 16 + l15][kt * 32 + lhi * 8]);
                acc0 = __builtin_amdgcn_mfma_f32_16x16x32_bf16(
                           a, w2f[kt][0], acc0, 0, 0, 0);
                acc1 = __builtin_amdgcn_mfma_f32_16x16x32_bf16(
                           a, w2f[kt][1], acc1, 0, 0, 0);
            }
            #pragma unroll
            for (int r = 0; r < 4; ++r) {
                H2s[m * 16 + lhi * 4 + r][(2 * w) * 16 + l15] =
                    (__bf16)fmaxf(acc0[r], 0.0f);
                H2s[m * 16 + lhi * 4 + r][(2 * w + 1) * 16 + l15] =
                    (__bf16)fmaxf(acc1[r], 0.0f);
            }
        }

        // ---- stage next tile into the other X buffer -----------------------
        if (havenext) write_x(buf ^ 1);

        __syncthreads();   // (3) H2s ready; Xs[buf^1] staged

        // ---- layer 3: vel = (H2 @ W3 + b3)/mu; wave w -> edges 16w..16w+15 -
        f32x4 acc3 = { 0.0f, 0.0f, 0.0f, 0.0f };
        #pragma unroll
        for (int kt = 0; kt < 4; ++kt) {
            const bf16x8 a = *reinterpret_cast<const bf16x8*>(
                &H2s[w * 16 + l15][kt * 32 + lhi * 8]);
            acc3 = __builtin_amdgcn_mfma_f32_16x16x32_bf16(
                       a, w3f[kt], acc3, 0, 0, 0);
        }
        if (l15 < FDOF) {
            #pragma unroll
            for (int r = 0; r < 4; ++r) {
                const int e = w * 16 + lhi * 4 + r;
                atomicAdd(&out[(size_t)tgts[buf][e] * FDOF + l15],
                          (acc3[r] + b3v) * inv_mu);
            }
        }
        buf ^= 1;
    }
}

extern "C" void kernel_launch(void* const* d_in, const int* in_sizes, int n_in,
                              void* d_out, int out_size, void* d_ws, size_t ws_size,
                              hipStream_t stream) {
    const float* rel   = (const float*)d_in[0];
    const int*   tgt   = (const int*)d_in[1];
    const int*   src   = (const int*)d_in[2];
    const float* force = (const float*)d_in[3];
    const float* visc  = (const float*)d_in[4];
    const float* med   = (const float*)d_in[5];
    const float* con   = (const float*)d_in[6];
    const float* W1    = (const float*)d_in[7];
    const float* b1    = (const float*)d_in[8];
    const float* W2    = (const float*)d_in[9];
    const float* b2    = (const float*)d_in[10];
    const float* W3    = (const float*)d_in[11];
    const float* b3    = (const float*)d_in[12];
    float* out = (float*)d_out;

    pairvel_zero_kernel<<<(out_size + 255) / 256, 256, 0, stream>>>(out, out_size);
    pairvel_mfma_kernel<<<GRID, 256, 0, stream>>>(
        rel, tgt, src, force, visc, med, con, W1, b1, W2, b2, W3, b3, out);
}

// Round 6
// 49.346 us; speedup vs baseline: 1.1041x; 1.1041x over previous
//
#include <hip/hip_runtime.h>

#define NPART 4096
#define E_TOT 262144
#define HID   128
#define FDOF  6
#define BM    64                 // edges per block-iteration
#define NIT   (E_TOT / BM)       // 4096
#define GRID  1024               // NIT/GRID = 4 iters/block exactly (balanced)
#define XPAD  40                 // 80 B rows = 5x16 -> aligned b128 reads
#define HPAD  136                // 272 B rows = 17x16 -> aligned

typedef __bf16 bf16x8 __attribute__((ext_vector_type(8)));
typedef float  f32x4  __attribute__((ext_vector_type(4)));

__global__ void pairvel_zero_kernel(float* __restrict__ out, int n) {
    const int i = blockIdx.x * blockDim.x + threadIdx.x;
    if (i < n) out[i] = 0.0f;
}

// 4-wave block; wave w owns hidden cols [32w,32w+32) for L1/L2, edge rows
// [16w,16w+16) for L3. Weights = per-wave MFMA B-fragments (56 VGPRs).
// Round 6: GRID back to 1024 (round 5's 768 was tail-imbalanced);
// LDS 40.2->27.5 KB by merging H2 into H1 (L2 accumulates in registers,
// writes back after a barrier); gather prefetch issued a FULL iteration
// ahead (depth-2 register pipeline) so HBM/L3 latency hides completely.
__global__ __launch_bounds__(256) void pairvel_mfma_kernel(
    const float* __restrict__ rel,       // [N,N,3]
    const int*   __restrict__ tgt,       // [E]
    const int*   __restrict__ src,       // [E]
    const float* __restrict__ force,     // [N,6]
    const float* __restrict__ visc,
    const float* __restrict__ medianp,
    const float* __restrict__ contactp,
    const float* __restrict__ W1,        // [19,128]
    const float* __restrict__ b1,        // [128]
    const float* __restrict__ W2,        // [128,128]
    const float* __restrict__ b2,        // [128]
    const float* __restrict__ W3,        // [128,6]
    const float* __restrict__ b3,        // [6]
    float* __restrict__ out)             // [N,6]
{
    const int tid = threadIdx.x;
    const int w   = tid >> 6;     // wave 0..3
    const int l   = tid & 63;     // lane
    const int l15 = l & 15;
    const int lhi = l >> 4;       // 0..3

    // ---- weight fragments (B operand: lane l holds W[kt*32+lhi*8+r][n16+l15])
    bf16x8 w1f[2], w2f[4][2], w3f[4];
    #pragma unroll
    for (int nb = 0; nb < 2; ++nb) {
        const int n = (2 * w + nb) * 16 + l15;
        #pragma unroll
        for (int r = 0; r < 8; ++r) {
            const int k = lhi * 8 + r;
            w1f[nb][r] = (k < 19) ? (__bf16)W1[k * HID + n] : (__bf16)0.0f;
        }
    }
    #pragma unroll
    for (int kt = 0; kt < 4; ++kt)
        #pragma unroll
        for (int nb = 0; nb < 2; ++nb) {
            const int n = (2 * w + nb) * 16 + l15;
            #pragma unroll
            for (int r = 0; r < 8; ++r)
                w2f[kt][nb][r] = (__bf16)W2[(kt * 32 + lhi * 8 + r) * HID + n];
        }
    #pragma unroll
    for (int kt = 0; kt < 4; ++kt)
        #pragma unroll
        for (int r = 0; r < 8; ++r) {
            const int k = kt * 32 + lhi * 8 + r;
            w3f[kt][r] = (l15 < FDOF) ? (__bf16)W3[k * FDOF + l15] : (__bf16)0.0f;
        }

    const float b1v0 = b1[(2 * w) * 16 + l15];
    const float b1v1 = b1[(2 * w + 1) * 16 + l15];
    const float b2v0 = b2[(2 * w) * 16 + l15];
    const float b2v1 = b2[(2 * w + 1) * 16 + l15];
    const float b3v  = (l15 < FDOF) ? b3[l15] : 0.0f;
    const float inv_mu  = 1.0f / visc[0];
    const float median  = medianp[0];
    const float contact = contactp[0];

    __shared__ __align__(16) __bf16 Xs[2][BM][XPAD];   // 10240 B
    __shared__ __align__(16) __bf16 Hs[BM][HPAD];      // 17408 B (H1 then H2)
    __shared__ int tgts[2][BM];                        //   512 B

    // zero X pad cols 19..31 in both buffers once
    for (int t = tid; t < 2 * BM * 13; t += 256) {
        const int b = t / (BM * 13), rem = t % (BM * 13);
        Xs[b][rem / 13][19 + rem % 13] = (__bf16)0.0f;
    }

    // ---- per-thread prefetch state (8 scalars) -----------------------------
    int   p_i0 = 0;
    float p_v0 = 0.f, p_v1 = 0.f, p_v2 = 0.f;
    float p_f3 = 0.f, p_f4 = 0.f, p_f5 = 0.f;

    auto gather_load = [&](int e0n) {
        if (tid < BM) {
            const int eg = e0n + tid;
            p_i0 = tgt[eg];
            const int sg = src[eg];
            const float* rp = rel + ((size_t)p_i0 * NPART + sg) * 3;
            p_v0 = rp[0]; p_v1 = rp[1]; p_v2 = rp[2];
        } else if (tid < 2 * BM) {
            const int eg = e0n + (tid - BM);
            const float2* f2 =
                reinterpret_cast<const float2*>(force + (size_t)tgt[eg] * FDOF);
            const float2 u0 = f2[0], u1 = f2[1], u2 = f2[2];
            p_v0 = u0.x; p_v1 = u0.y; p_v2 = u1.x;
            p_f3 = u1.y; p_f4 = u2.x; p_f5 = u2.y;
        } else if (tid < 3 * BM) {
            const int eg = e0n + (tid - 2 * BM);
            const float2* f2 =
                reinterpret_cast<const float2*>(force + (size_t)src[eg] * FDOF);
            const float2 u0 = f2[0], u1 = f2[1], u2 = f2[2];
            p_v0 = u0.x; p_v1 = u0.y; p_v2 = u1.x;
            p_f3 = u1.y; p_f4 = u2.x; p_f5 = u2.y;
        }
    };

    auto write_x = [&](int b) {
        if (tid < BM) {
            const int e = tid;
            tgts[b][e] = p_i0;
            const float dist = fmaxf(
                sqrtf(p_v0 * p_v0 + p_v1 * p_v1 + p_v2 * p_v2), 1e-8f);
            const float rs = (dist - median) * (dist - median);
            Xs[b][e][0] = (__bf16)p_v0;
            Xs[b][e][1] = (__bf16)p_v1;
            Xs[b][e][2] = (__bf16)p_v2;
            Xs[b][e][3] = (__bf16)dist;
            Xs[b][e][4] = (__bf16)rs;
            Xs[b][e][5] = (__bf16)(rs * rs);
            Xs[b][e][6] = (__bf16)(dist - contact);
        } else if (tid < 2 * BM) {
            const int e = tid - BM;
            Xs[b][e][7]  = (__bf16)p_v0;
            Xs[b][e][8]  = (__bf16)p_v1;
            Xs[b][e][9]  = (__bf16)p_v2;
            Xs[b][e][10] = (__bf16)p_f3;
            Xs[b][e][11] = (__bf16)p_f4;
            Xs[b][e][12] = (__bf16)p_f5;
        } else if (tid < 3 * BM) {
            const int e = tid - 2 * BM;
            Xs[b][e][13] = (__bf16)p_v0;
            Xs[b][e][14] = (__bf16)p_v1;
            Xs[b][e][15] = (__bf16)p_v2;
            Xs[b][e][16] = (__bf16)p_f3;
            Xs[b][e][17] = (__bf16)p_f4;
            Xs[b][e][18] = (__bf16)p_f5;
        }
    };

    // ---- prologue: stage iter-0 tile; issue iter-1 loads -------------------
    gather_load(blockIdx.x * BM);
    write_x(0);
    if (blockIdx.x + GRID < NIT) gather_load((blockIdx.x + GRID) * BM);
    int buf = 0;

    for (int it = blockIdx.x; it < NIT; it += GRID) {
        __syncthreads();   // (A) Xs[buf]/tgts[buf] staged; Hs free (L3 done)

        // ---- layer 1: H1 = relu(X @ W1 + b1) -> Hs -------------------------
        #pragma unroll
        for (int m = 0; m < 4; ++m) {
            const bf16x8 a = *reinterpret_cast<const bf16x8*>(
                &Xs[buf][m * 16 + l15][lhi * 8]);
            #pragma unroll
            for (int nb = 0; nb < 2; ++nb) {
                const float bv = nb ? b1v1 : b1v0;
                f32x4 acc = { bv, bv, bv, bv };
                acc = __builtin_amdgcn_mfma_f32_16x16x32_bf16(
                          a, w1f[nb], acc, 0, 0, 0);
                #pragma unroll
                for (int r = 0; r < 4; ++r)
                    Hs[m * 16 + lhi * 4 + r][(2 * w + nb) * 16 + l15] =
                        (__bf16)fmaxf(acc[r], 0.0f);
            }
        }
        __syncthreads();   // (B) H1 ready

        // ---- layer 2: accs = H1 @ W2 + b2 (registers only) -----------------
        f32x4 accs[4][2];
        #pragma unroll
        for (int m = 0; m < 4; ++m) {
            accs[m][0] = (f32x4){ b2v0, b2v0, b2v0, b2v0 };
            accs[m][1] = (f32x4){ b2v1, b2v1, b2v1, b2v1 };
            #pragma unroll
            for (int kt = 0; kt < 4; ++kt) {
                const bf16x8 a = *reinterpret_cast<const bf16x8*>(
                    &Hs[m * 16 + l15][kt * 32 + lhi * 8]);
                accs[m][0] = __builtin_amdgcn_mfma_f32_16x16x32_bf16(
                                 a, w2f[kt][0], accs[m][0], 0, 0, 0);
                accs[m][1] = __builtin_amdgcn_mfma_f32_16x16x32_bf16(
                                 a, w2f[kt][1], accs[m][1], 0, 0, 0);
            }
        }
        __syncthreads();   // (C) all H1 reads done -> Hs reusable

        // ---- write H2 into Hs; stage next X; issue next-next gather --------
        #pragma unroll
        for (int m = 0; m < 4; ++m)
            #pragma unroll
            for (int nb = 0; nb < 2; ++nb)
                #pragma unroll
                for (int r = 0; r < 4; ++r)
                    Hs[m * 16 + lhi * 4 + r][(2 * w + nb) * 16 + l15] =
                        (__bf16)fmaxf(accs[m][nb][r], 0.0f);

        if (it + GRID < NIT) write_x(buf ^ 1);          // consume prefetch regs
        if (it + 2 * GRID < NIT)
            gather_load((it + 2 * GRID) * BM);           // issue depth-2 loads
        __syncthreads();   // (D) H2 ready; Xs[buf^1] staged

        // ---- layer 3: vel = (H2 @ W3 + b3)/mu; wave w -> edges 16w..16w+15 -
        f32x4 acc3 = { 0.0f, 0.0f, 0.0f, 0.0f };
        #pragma unroll
        for (int kt = 0; kt < 4; ++kt) {
            const bf16x8 a = *reinterpret_cast<const bf16x8*>(
                &Hs[w * 16 + l15][kt * 32 + lhi * 8]);
            acc3 = __builtin_amdgcn_mfma_f32_16x16x32_bf16(
                       a, w3f[kt], acc3, 0, 0, 0);
        }
        if (l15 < FDOF) {
            #pragma unroll
            for (int r = 0; r < 4; ++r) {
                const int e = w * 16 + lhi * 4 + r;
                atomicAdd(&out[(size_t)tgts[buf][e] * FDOF + l15],
                          (acc3[r] + b3v) * inv_mu);
            }
        }
        buf ^= 1;
    }
}

extern "C" void kernel_launch(void* const* d_in, const int* in_sizes, int n_in,
                              void* d_out, int out_size, void* d_ws, size_t ws_size,
                              hipStream_t stream) {
    const float* rel   = (const float*)d_in[0];
    const int*   tgt   = (const int*)d_in[1];
    const int*   src   = (const int*)d_in[2];
    const float* force = (const float*)d_in[3];
    const float* visc  = (const float*)d_in[4];
    const float* med   = (const float*)d_in[5];
    const float* con   = (const float*)d_in[6];
    const float* W1    = (const float*)d_in[7];
    const float* b1    = (const float*)d_in[8];
    const float* W2    = (const float*)d_in[9];
    const float* b2    = (const float*)d_in[10];
    const float* W3    = (const float*)d_in[11];
    const float* b3    = (const float*)d_in[12];
    float* out = (float*)d_out;

    pairvel_zero_kernel<<<(out_size + 255) / 256, 256, 0, stream>>>(out, out_size);
    pairvel_mfma_kernel<<<GRID, 256, 0, stream>>>(
        rel, tgt, src, force, visc, med, con, W1, b1, W2, b2, W3, b3, out);
}